// Round 1
// baseline (440.446 us; speedup 1.0000x reference)
//
#include <hip/hip_runtime.h>

// LengthRegulator: B=32, T=1024, D=384, MAXLEN=8192 (fixed by the harness).
// out[b,p,:] = x[b, searchsorted_right(cum[b], p), :] for p < total[b], else 0.
// Inverted view: frame t owns output rows [cum[t-1], cum[t]) — exact partition.

#define B_   32
#define T_   1024
#define D_   384
#define ML_  8192
#define D4_  (D_ / 4)   // 96 float4 per row

// --- Kernel 1: per-batch inclusive scan of clamped durations -------------
__global__ void lr_scan(const int* __restrict__ dur,
                        int* __restrict__ cum,
                        float* __restrict__ total_out) {
    __shared__ int s[T_];
    const int b = blockIdx.x;
    const int t = threadIdx.x;
    int d = dur[b * T_ + t];
    d = d > 0 ? d : 0;
    s[t] = d;
    __syncthreads();
    // Hillis-Steele inclusive scan over 1024 elements
    for (int off = 1; off < T_; off <<= 1) {
        int v = (t >= off) ? s[t - off] : 0;
        __syncthreads();
        s[t] += v;
        __syncthreads();
    }
    cum[b * T_ + t] = s[t];
    if (t == T_ - 1) {
        // d_out is read back as one flat float32 buffer -> store total as float
        total_out[b] = (float)s[t];
    }
}

// --- Kernel 2: expansion scatter — one block per input frame -------------
__global__ __launch_bounds__(128) void lr_expand(const float4* __restrict__ x,
                                                 const int* __restrict__ cum,
                                                 float4* __restrict__ out) {
    const int f = blockIdx.x;        // global frame id in [0, B*T)
    const int t = f & (T_ - 1);
    const int b = f >> 10;
    int end   = cum[f];
    int start = (t == 0) ? 0 : cum[f - 1];
    if (end > ML_) end = ML_;        // total may exceed MAXLEN (max 15360)
    if (start >= end) return;        // dur==0 or fully clipped
    const int tid = threadIdx.x;
    if (tid >= D4_) return;          // 96 of 128 lanes carry the row
    const float4 v = x[f * D4_ + tid];
    float4* o = out + (size_t)(b * ML_ + start) * D4_ + tid;
    for (int p = start; p < end; ++p) {
        *o = v;
        o += D4_;
    }
}

// --- Kernel 3: zero-fill invalid tail rows [total, MAXLEN) ---------------
__global__ void lr_zfill(const int* __restrict__ cum,
                         float4* __restrict__ out) {
    const int b = blockIdx.y;
    int total = cum[b * T_ + T_ - 1];
    const int startRow = total < ML_ ? total : ML_;
    const int nfill = (ML_ - startRow) * D4_;
    const int base = (b * ML_ + startRow) * D4_;
    const int stride = gridDim.x * blockDim.x;
    const float4 z = make_float4(0.f, 0.f, 0.f, 0.f);
    for (int i = blockIdx.x * blockDim.x + threadIdx.x; i < nfill; i += stride)
        out[base + i] = z;
}

extern "C" void kernel_launch(void* const* d_in, const int* in_sizes, int n_in,
                              void* d_out, int out_size, void* d_ws, size_t ws_size,
                              hipStream_t stream) {
    const float* x   = (const float*)d_in[0];   // (B, T, D) fp32
    const int*   dur = (const int*)d_in[1];     // (B, T) int32
    // d_in[2] = max_len scalar (always 8192 here; hardcoded)

    float* out       = (float*)d_out;                       // (B, ML, D) fp32
    float* total_out = out + (size_t)B_ * ML_ * D_;         // (B,) stored as fp32
    int*   cum       = (int*)d_ws;                          // (B, T) scratch

    lr_scan<<<B_, T_, 0, stream>>>(dur, cum, total_out);
    lr_expand<<<B_ * T_, 128, 0, stream>>>((const float4*)x, cum, (float4*)out);
    lr_zfill<<<dim3(64, B_), 256, 0, stream>>>(cum, (float4*)out);
}